// Round 7
// baseline (424.654 us; speedup 1.0000x reference)
//
#include <hip/hip_runtime.h>
#include <math.h>

// ---------------------------------------------------------------------------
// SharedAttentionProcessor: B=4, H=20, S=1024, C=1280, hd=64
// R7: attention re-tiled to 32-key tiles -> 24 KB LDS -> 6 blocks/CU
// (occupancy was the R6 regression); P transform at exact LDS data floor
// (b128 write + 2x b64 read, granule XOR swizzle, zero above-floor
// conflicts); single barrier per tile retained.
// ---------------------------------------------------------------------------

typedef __bf16 bf16x8 __attribute__((ext_vector_type(8)));
typedef float f32x4 __attribute__((ext_vector_type(4)));
typedef unsigned short u16x8 __attribute__((ext_vector_type(8)));

#define BDIM 256

__device__ inline unsigned short f2bf(float f) {
  unsigned int u = __float_as_uint(f);
  u += 0x7fffu + ((u >> 16) & 1u);   // RNE (inputs finite)
  return (unsigned short)(u >> 16);
}
__device__ inline unsigned int pack_bf2(float lo, float hi) {
  return (unsigned int)f2bf(lo) | ((unsigned int)f2bf(hi) << 16);
}
__device__ inline float bf2f(unsigned short h) {
  return __uint_as_float(((unsigned int)h) << 16);
}

__device__ inline void gl_lds16(const unsigned short* g, unsigned short* l) {
  __builtin_amdgcn_global_load_lds(
      (const __attribute__((address_space(1))) unsigned int*)g,
      (__attribute__((address_space(3))) unsigned int*)l, 16, 0, 0);
}

// --------------------------- fused fp32 -> bf16 convert ---------------------
__global__ __launch_bounds__(BDIM) void k_convert_all(
    const float* __restrict__ X, const float* __restrict__ Wq,
    const float* __restrict__ Wk, const float* __restrict__ Wv,
    const float* __restrict__ Wo, unsigned short* __restrict__ Xbf,
    unsigned short* __restrict__ Wcat, unsigned short* __restrict__ Wobf) {
  const int idx = blockIdx.x * BDIM + threadIdx.x;
  const float* src;
  unsigned short* dst;
  int off;
  if (idx < 1310720) {
    src = X; dst = Xbf; off = idx;
  } else {
    const int r = idx - 1310720;
    const int which = r / 409600;
    off = r - which * 409600;
    src = (which == 0) ? Wq : (which == 1) ? Wk : (which == 2) ? Wv : Wo;
    dst = (which < 3) ? Wcat + (size_t)which * 1638400 : Wobf;
  }
  const float4 v = ((const float4*)src)[off];
  ushort4 o;
  o.x = f2bf(v.x); o.y = f2bf(v.y); o.z = f2bf(v.z); o.w = f2bf(v.w);
  ((ushort4*)dst)[off] = o;
}

// --------------------------- bf16 GEMM 128x128, BK=64 (QKV) -----------------
__global__ __launch_bounds__(BDIM) void k_gemm_bf16(
    const unsigned short* __restrict__ A, const unsigned short* __restrict__ B,
    unsigned short* __restrict__ Cbf, int M, int N, int K) {
  __shared__ unsigned short As[2][128 * 32];
  __shared__ unsigned short Bs[2][128 * 32];
  const int t = threadIdx.x;
  const int w = t >> 6, lane = t & 63, quad = lane >> 4, l16 = lane & 15;
  const int wm = (w >> 1) << 6, wn = (w & 1) << 6;
  const int mBase = blockIdx.x * 128, nBase = blockIdx.y * 128;

  f32x4 acc[4][4];
#pragma unroll
  for (int i = 0; i < 4; i++)
#pragma unroll
    for (int j = 0; j < 4; j++) acc[i][j] = (f32x4){0.f, 0.f, 0.f, 0.f};

  const int r0 = t >> 2;
  const int kk0 = (t & 3) * 8;

  for (int k0 = 0; k0 < K; k0 += 64) {
    const unsigned short* Ab = A + (size_t)(mBase + r0) * K + k0 + kk0;
    const unsigned short* Bb = B + (size_t)(nBase + r0) * K + k0 + kk0;
    gl_lds16(Ab, As[0] + t * 8);
    gl_lds16(Ab + (size_t)64 * K, As[0] + (t + 256) * 8);
    gl_lds16(Ab + 32, As[1] + t * 8);
    gl_lds16(Ab + (size_t)64 * K + 32, As[1] + (t + 256) * 8);
    gl_lds16(Bb, Bs[0] + t * 8);
    gl_lds16(Bb + (size_t)64 * K, Bs[0] + (t + 256) * 8);
    gl_lds16(Bb + 32, Bs[1] + t * 8);
    gl_lds16(Bb + (size_t)64 * K + 32, Bs[1] + (t + 256) * 8);
    __syncthreads();
    bf16x8 af[2][4], bfr[2][4];
#pragma unroll
    for (int hh = 0; hh < 2; hh++)
#pragma unroll
      for (int i = 0; i < 4; i++) {
        af[hh][i] = *(const bf16x8*)(As[hh] + (wm + i * 16 + l16) * 32 + quad * 8);
        bfr[hh][i] = *(const bf16x8*)(Bs[hh] + (wn + i * 16 + l16) * 32 + quad * 8);
      }
#pragma unroll
    for (int hh = 0; hh < 2; hh++)
#pragma unroll
      for (int mi = 0; mi < 4; mi++)
#pragma unroll
        for (int ni = 0; ni < 4; ni++)
          acc[mi][ni] = __builtin_amdgcn_mfma_f32_16x16x32_bf16(
              af[hh][mi], bfr[hh][ni], acc[mi][ni], 0, 0, 0);
    __syncthreads();
  }

#pragma unroll
  for (int mi = 0; mi < 4; mi++)
#pragma unroll
    for (int r = 0; r < 4; r++) {
      const int row = mBase + wm + mi * 16 + quad * 4 + r;
#pragma unroll
      for (int ni = 0; ni < 4; ni++)
        Cbf[(size_t)row * N + nBase + wn + ni * 16 + l16] = f2bf(acc[mi][ni][r]);
    }
}

// --------------------------- bf16 GEMM 64x128, BK=64 (out proj) -------------
__global__ __launch_bounds__(BDIM) void k_gemm_64x128(
    const unsigned short* __restrict__ A, const unsigned short* __restrict__ B,
    float* __restrict__ Cf, const float* __restrict__ bias, int M, int N,
    int K) {
  __shared__ unsigned short As[2][64 * 32];
  __shared__ unsigned short Bs[2][128 * 32];
  const int t = threadIdx.x;
  const int w = t >> 6, lane = t & 63, quad = lane >> 4, l16 = lane & 15;
  const int wm = (w >> 1) << 5, wn = (w & 1) << 6;
  const int mBase = blockIdx.x * 64, nBase = blockIdx.y * 128;

  f32x4 acc[2][4];
#pragma unroll
  for (int i = 0; i < 2; i++)
#pragma unroll
    for (int j = 0; j < 4; j++) acc[i][j] = (f32x4){0.f, 0.f, 0.f, 0.f};

  const int r0 = t >> 2;
  const int kk0 = (t & 3) * 8;

  for (int k0 = 0; k0 < K; k0 += 64) {
    const unsigned short* Ab = A + (size_t)(mBase + r0) * K + k0 + kk0;
    const unsigned short* Bb = B + (size_t)(nBase + r0) * K + k0 + kk0;
    gl_lds16(Ab, As[0] + t * 8);
    gl_lds16(Ab + 32, As[1] + t * 8);
    gl_lds16(Bb, Bs[0] + t * 8);
    gl_lds16(Bb + (size_t)64 * K, Bs[0] + (t + 256) * 8);
    gl_lds16(Bb + 32, Bs[1] + t * 8);
    gl_lds16(Bb + (size_t)64 * K + 32, Bs[1] + (t + 256) * 8);
    __syncthreads();
    bf16x8 af[2][2], bfr[2][4];
#pragma unroll
    for (int hh = 0; hh < 2; hh++) {
#pragma unroll
      for (int i = 0; i < 2; i++)
        af[hh][i] = *(const bf16x8*)(As[hh] + (wm + i * 16 + l16) * 32 + quad * 8);
#pragma unroll
      for (int i = 0; i < 4; i++)
        bfr[hh][i] = *(const bf16x8*)(Bs[hh] + (wn + i * 16 + l16) * 32 + quad * 8);
    }
#pragma unroll
    for (int hh = 0; hh < 2; hh++)
#pragma unroll
      for (int mi = 0; mi < 2; mi++)
#pragma unroll
        for (int ni = 0; ni < 4; ni++)
          acc[mi][ni] = __builtin_amdgcn_mfma_f32_16x16x32_bf16(
              af[hh][mi], bfr[hh][ni], acc[mi][ni], 0, 0, 0);
    __syncthreads();
  }

#pragma unroll
  for (int mi = 0; mi < 2; mi++)
#pragma unroll
    for (int r = 0; r < 4; r++) {
      const int row = mBase + wm + mi * 16 + quad * 4 + r;
#pragma unroll
      for (int ni = 0; ni < 4; ni++) {
        const int col = nBase + wn + ni * 16 + l16;
        Cf[(size_t)row * N + col] = acc[mi][ni][r] + bias[col];
      }
    }
}

// --------------------------- adain stats (two-stage) ------------------------
__global__ __launch_bounds__(320) void k_stats1(
    const unsigned short* __restrict__ QKV, float* __restrict__ psum,
    float* __restrict__ psq) {
  const int z = blockIdx.y, which = z >> 2, b = z & 3;
  const int c = threadIdx.x * 4;
  const size_t base =
      (size_t)(b * 1024 + blockIdx.x * 32) * 3840 + which * 1280 + c;
  float4 s = {0.f, 0.f, 0.f, 0.f}, s2 = {0.f, 0.f, 0.f, 0.f};
#pragma unroll 8
  for (int i = 0; i < 32; ++i) {
    const ushort4 xv = *(const ushort4*)(QKV + base + (size_t)i * 3840);
    const float x0 = bf2f(xv.x), x1 = bf2f(xv.y), x2 = bf2f(xv.z),
                x3 = bf2f(xv.w);
    s.x += x0; s.y += x1; s.z += x2; s.w += x3;
    s2.x = fmaf(x0, x0, s2.x); s2.y = fmaf(x1, x1, s2.y);
    s2.z = fmaf(x2, x2, s2.z); s2.w = fmaf(x3, x3, s2.w);
  }
  const size_t o = ((size_t)z * 32 + blockIdx.x) * 1280 + c;
  *(float4*)(psum + o) = s;
  *(float4*)(psq + o) = s2;
}

__global__ __launch_bounds__(BDIM) void k_stats2(
    const float* __restrict__ psum, const float* __restrict__ psq,
    float* __restrict__ stats) {
  const int z = blockIdx.y, which = z >> 2, b = z & 3;
  const int c = blockIdx.x * 256 + threadIdx.x;
  float s = 0.f, s2 = 0.f;
#pragma unroll
  for (int j = 0; j < 32; ++j) {
    s += psum[((size_t)z * 32 + j) * 1280 + c];
    s2 += psq[((size_t)z * 32 + j) * 1280 + c];
  }
  const float mean = s * (1.0f / 1024.0f);
  const float var = (s2 - 1024.0f * mean * mean) * (1.0f / 1023.0f);
  stats[((which * 2 + 0) * 4 + b) * 1280 + c] = mean;
  stats[((which * 2 + 1) * 4 + b) * 1280 + c] = sqrtf(var + 1e-5f);
}

// --------------------- adain apply + V transpose (merged) -------------------
__global__ __launch_bounds__(BDIM) void k_adain_vt(
    const unsigned short* __restrict__ QKV, const float* __restrict__ stats,
    unsigned short* __restrict__ qn, unsigned short* __restrict__ kn,
    unsigned short* __restrict__ vt) {
  __shared__ unsigned short tile[64][65];
  const int bx = blockIdx.x;
  if (bx < 10240) {
    const int which = bx / 5120;
    const int rem = bx - which * 5120;
    const int b = rem / 1280;
    const int xb = rem - b * 1280;
    const int idx = xb * BDIM + threadIdx.x;  // [0, 327680)
    const int s = idx / 320;
    const int c = (idx - s * 320) * 4;
    const int sb = (b < 2) ? 0 : 2;
    const ushort4 xv = *(const ushort4*)(QKV + ((size_t)(b * 1024 + s)) * 3840 +
                                         which * 1280 + c);
    const float4 mean =
        *(const float4*)(stats + ((which * 2 + 0) * 4 + b) * 1280 + c);
    const float4 stdv =
        *(const float4*)(stats + ((which * 2 + 1) * 4 + b) * 1280 + c);
    const float4 meanS =
        *(const float4*)(stats + ((which * 2 + 0) * 4 + sb) * 1280 + c);
    const float4 stdS =
        *(const float4*)(stats + ((which * 2 + 1) * 4 + sb) * 1280 + c);
    ushort4 o;
    o.x = f2bf((bf2f(xv.x) - mean.x) / stdv.x * stdS.x + meanS.x);
    o.y = f2bf((bf2f(xv.y) - mean.y) / stdv.y * stdS.y + meanS.y);
    o.z = f2bf((bf2f(xv.z) - mean.z) / stdv.z * stdS.z + meanS.z);
    o.w = f2bf((bf2f(xv.w) - mean.w) / stdv.w * stdS.w + meanS.w);
    unsigned short* dst = (which == 0) ? qn : kn;
    *(ushort4*)(dst + ((size_t)(b * 1024 + s)) * 1280 + c) = o;
  } else {
    const int tb = bx - 10240;           // [0,1280)
    const int b = tb / 320;
    const int r2 = tb - b * 320;
    const int c0 = (r2 / 16) * 64;
    const int s0 = (r2 & 15) * 64;
    const int t = threadIdx.x;
    const int r = t >> 2, seg = (t & 3) * 16;
    const size_t goff = ((size_t)(b * 1024 + s0 + r)) * 3840 + 2560 + c0 + seg;
    const u16x8 va = *(const u16x8*)(QKV + goff);
    const u16x8 vb = *(const u16x8*)(QKV + goff + 8);
#pragma unroll
    for (int j = 0; j < 8; j++) {
      tile[r][seg + j] = va[j];
      tile[r][seg + 8 + j] = vb[j];
    }
    __syncthreads();
    u16x8 o0, o1;
#pragma unroll
    for (int j = 0; j < 8; j++) {
      o0[j] = tile[seg + j][r];
      o1[j] = tile[seg + 8 + j][r];
    }
    const size_t ooff = ((size_t)(b * 1280 + c0 + r)) * 1024 + s0 + seg;
    *(u16x8*)(vt + ooff) = o0;
    *(u16x8*)(vt + ooff + 8) = o1;
  }
}

// --------------------------- flash attention --------------------------------
// grid (8, 20, 12): z -> (b, chunk); each block: 16 iterations of 32 keys
// (512 keys). 24 KB LDS -> 6 blocks/CU. Single barrier per iteration,
// K+V double-buffered. P transform at exact LDS data floor:
//   write: one b128/lane/g, granule phys = quad ^ (l16&3)
//   read:  two b64/lane/g  (writer quads (2q)&3,(2q+1)&3, half = q>>1)
__global__ __launch_bounds__(BDIM, 6) void k_attn(
    const unsigned short* __restrict__ qn, const unsigned short* __restrict__ kn,
    const unsigned short* __restrict__ vt, unsigned short* __restrict__ Opart,
    float* __restrict__ Lpart) {
  const int S = 1024, C = 1280;
  const int qt = blockIdx.x, h = blockIdx.y, zs = blockIdx.z;
  int b, chunk;
  if (zs < 2)      { b = 0; chunk = zs; }
  else if (zs < 6) { b = 1; chunk = zs - 2; }
  else if (zs < 8) { b = 2; chunk = zs - 6; }
  else             { b = 3; chunk = zs - 8; }
  const int itBeg = chunk * 16;  // iteration index, 32-key units
  const int t = threadIdx.x, w = t >> 6, lane = t & 63;
  const int quad = lane >> 4, l16 = lane & 15;
  const int bstyle = (b < 2) ? 0 : 2;
  const int qrow = qt * 128 + w * 32;

  __shared__ unsigned short Ks[2][2048];      // [buf][half*1024+key*32+dim] 8KB
  __shared__ unsigned short Vs[2][2048];      // [buf][dim*32+key]           8KB
  __shared__ unsigned short Plds[4][32][32];  // [wave][query][swz keys]     8KB

  bf16x8 aq[2][2];
#pragma unroll
  for (int g = 0; g < 2; ++g) {
    const size_t qoff =
        ((size_t)(b * S + qrow + g * 16 + l16)) * C + h * 64 + quad * 8;
    aq[g][0] = *(const bf16x8*)(qn + qoff);
    aq[g][1] = *(const bf16x8*)(qn + qoff + 32);
  }

  bf16x8 ones;
#pragma unroll
  for (int i = 0; i < 8; ++i) ones[i] = (__bf16)1.0f;

  f32x4 o[2][4], lsum[2];
#pragma unroll
  for (int g = 0; g < 2; ++g) {
    lsum[g] = (f32x4){0.f, 0.f, 0.f, 0.f};
#pragma unroll
    for (int i = 0; i < 4; i++) o[g][i] = (f32x4){0.f, 0.f, 0.f, 0.f};
  }

  // staging coords: K tile 32 keys x 64 dims (split halves); V 64 dims x 32 k
  const int kr = (t & 127) >> 2;                    // key row 0..31
  const int kc = (t & 3) * 8 + (t >> 7) * 32;       // dim col
  const int vr = t >> 2;                            // dim row 0..63
  const int vc = (t & 3) * 8;                       // key col

  auto stage = [&](int buf, int it) {
    const int bs = (it < 32) ? b : bstyle;
    const int sk = (it & 31) * 32;
    gl_lds16(kn + (size_t)(bs * S + sk + kr) * C + h * 64 + kc, Ks[buf] + t * 8);
    gl_lds16(vt + (size_t)(bs * C + h * 64 + vr) * S + sk + vc, Vs[buf] + t * 8);
  };

  stage(0, itBeg);

  const float SCALE2 = 0.125f * 1.44269504088896341f;
  const int swz = l16 & 3;
  const int h_ = quad >> 1;
  const int qw0 = (2 * quad) & 3, qw1 = (2 * quad + 1) & 3;

  for (int i = 0; i < 16; ++i) {
    const int it = itBeg + i;
    const int buf = i & 1;
    __syncthreads();  // stage(buf) landed; reads of buf^1 finished
    if (i + 1 < 16) stage(buf ^ 1, it + 1);

    const float bias2 = (it >= 32) ? 1.0f : 0.0f;

    // S^T: D[m=key nt*16+quad*4+r][n=query l16], nt=0..1
    f32x4 z2[2][2];
#pragma unroll
    for (int nt = 0; nt < 2; ++nt) {
      const bf16x8 bk0 = *(const bf16x8*)(Ks[buf] + (nt * 16 + l16) * 32 + quad * 8);
      const bf16x8 bk1 =
          *(const bf16x8*)(Ks[buf] + 1024 + (nt * 16 + l16) * 32 + quad * 8);
#pragma unroll
      for (int g = 0; g < 2; ++g) {
        f32x4 zz = (f32x4){0.f, 0.f, 0.f, 0.f};
        zz = __builtin_amdgcn_mfma_f32_16x16x32_bf16(bk0, aq[g][0], zz, 0, 0, 0);
        zz = __builtin_amdgcn_mfma_f32_16x16x32_bf16(bk1, aq[g][1], zz, 0, 0, 0);
        z2[g][nt] = zz;
      }
    }

    // exp2; pack this lane's 8 keys -> one b128 at swizzled granule
#pragma unroll
    for (int g = 0; g < 2; ++g) {
      uint4 pk;
      {
        const float e0 = exp2f(fmaf(z2[g][0][0], SCALE2, bias2));
        const float e1 = exp2f(fmaf(z2[g][0][1], SCALE2, bias2));
        const float e2 = exp2f(fmaf(z2[g][0][2], SCALE2, bias2));
        const float e3 = exp2f(fmaf(z2[g][0][3], SCALE2, bias2));
        pk.x = pack_bf2(e0, e1);
        pk.y = pack_bf2(e2, e3);
      }
      {
        const float e0 = exp2f(fmaf(z2[g][1][0], SCALE2, bias2));
        const float e1 = exp2f(fmaf(z2[g][1][1], SCALE2, bias2));
        const float e2 = exp2f(fmaf(z2[g][1][2], SCALE2, bias2));
        const float e3 = exp2f(fmaf(z2[g][1][3], SCALE2, bias2));
        pk.z = pack_bf2(e0, e1);
        pk.w = pack_bf2(e2, e3);
      }
      *(uint4*)(&Plds[w][g * 16 + l16][(quad ^ swz) * 8]) = pk;
    }

    // gather A-fragments (keys quad*8..+7 of query l16) and accumulate
#pragma unroll
    for (int g = 0; g < 2; ++g) {
      const uint2 lo =
          *(const uint2*)(&Plds[w][g * 16 + l16][(qw0 ^ swz) * 8 + h_ * 4]);
      const uint2 hi =
          *(const uint2*)(&Plds[w][g * 16 + l16][(qw1 ^ swz) * 8 + h_ * 4]);
      union { unsigned int u[4]; bf16x8 v; } pu;
      pu.u[0] = lo.x; pu.u[1] = lo.y; pu.u[2] = hi.x; pu.u[3] = hi.y;
      const bf16x8 pa = pu.v;
      lsum[g] = __builtin_amdgcn_mfma_f32_16x16x32_bf16(pa, ones, lsum[g], 0, 0, 0);
#pragma unroll
      for (int dt = 0; dt < 4; ++dt) {
        const bf16x8 vb =
            *(const bf16x8*)(Vs[buf] + (dt * 16 + l16) * 32 + quad * 8);
        o[g][dt] =
            __builtin_amdgcn_mfma_f32_16x16x32_bf16(pa, vb, o[g][dt], 0, 0, 0);
      }
    }
  }

  if (l16 == 0) {
#pragma unroll
    for (int g = 0; g < 2; ++g)
#pragma unroll
      for (int r = 0; r < 4; ++r)
        Lpart[((size_t)zs * 20 + h) * 1024 + qrow + g * 16 + quad * 4 + r] =
            lsum[g][r];
  }

  unsigned short* Op = Opart + (size_t)zs * 1024 * 1280;
#pragma unroll
  for (int g = 0; g < 2; ++g)
#pragma unroll
    for (int dt = 0; dt < 4; ++dt)
#pragma unroll
      for (int r = 0; r < 4; ++r)
        Op[(size_t)(qrow + g * 16 + quad * 4 + r) * 1280 + h * 64 + dt * 16 +
           l16] = f2bf(o[g][dt][r]);
}

// --------------------------- combine slice partials -------------------------
__global__ __launch_bounds__(BDIM) void k_combine(
    const unsigned short* __restrict__ Opart, const float* __restrict__ Lpart,
    unsigned short* __restrict__ attnb) {
  const int idx = blockIdx.x * BDIM + threadIdx.x;  // [0, 655360)
  const int row = idx / 160;
  const int c = (idx - row * 160) * 8;
  const int b = row >> 10, q = row & 1023, h = c >> 6;
  const int zb = (b >> 1) * 6 + (b & 1) * 2;  // 0,2,6,8
  const int ns = 2 + (b & 1) * 2;             // 2 or 4 slices
  float L = 0.f;
  float acc[8] = {0.f, 0.f, 0.f, 0.f, 0.f, 0.f, 0.f, 0.f};
  for (int s = 0; s < ns; ++s) {
    L += Lpart[((size_t)(zb + s) * 20 + h) * 1024 + q];
    const u16x8 v =
        *(const u16x8*)(Opart + (size_t)(zb + s) * 1310720 + (size_t)q * 1280 + c);
#pragma unroll
    for (int j = 0; j < 8; ++j) acc[j] += bf2f(v[j]);
  }
  const float rl = 1.0f / L;
  u16x8 o8;
#pragma unroll
  for (int j = 0; j < 8; ++j) o8[j] = f2bf(acc[j] * rl);
  *(u16x8*)(attnb + (size_t)row * 1280 + c) = o8;
}

// ---------------------------------------------------------------------------
extern "C" void kernel_launch(void* const* d_in, const int* in_sizes, int n_in,
                              void* d_out, int out_size, void* d_ws,
                              size_t ws_size, hipStream_t stream) {
  const float* X = (const float*)d_in[0];
  const float* Wq = (const float*)d_in[1];
  const float* Wk = (const float*)d_in[2];
  const float* Wv = (const float*)d_in[3];
  const float* Wo = (const float*)d_in[4];
  const float* bo = (const float*)d_in[5];
  float* out = (float*)d_out;

  char* ws = (char*)d_ws;
  size_t off = 0;
  auto alloc = [&](size_t bytes) {
    char* p = ws + off;
    off += (bytes + 255) & ~(size_t)255;
    return p;
  };
  unsigned short* Wcat = (unsigned short*)alloc(3840ull * 1280 * 2);
  unsigned short* Xbf = (unsigned short*)alloc(4096ull * 1280 * 2);
  unsigned short* QKV = (unsigned short*)alloc(4096ull * 3840 * 2);
  unsigned short* Wobf = (unsigned short*)alloc(1280ull * 1280 * 2);
  float* stats = (float*)alloc(2ull * 2 * 4 * 1280 * 4);
  unsigned short* qnb = (unsigned short*)alloc(4096ull * 1280 * 2);
  unsigned short* knb = (unsigned short*)alloc(4096ull * 1280 * 2);
  unsigned short* vtb = (unsigned short*)alloc(4096ull * 1280 * 2);
  unsigned short* attnb = (unsigned short*)alloc(4096ull * 1280 * 2);

  unsigned short* Opart = QKV;                        // 12 x 1024 x 1280 bf16
  float* Lpart = (float*)Wcat;                        // 12 x 20 x 1024 fp32
  float* psum = (float*)attnb;                        // 8 x 32 x 1280 fp32
  float* psq = (float*)(attnb + 4096ull * 1280 / 2);  // second half

  k_convert_all<<<11520, BDIM, 0, stream>>>(X, Wq, Wk, Wv, Wo, Xbf, Wcat, Wobf);
  k_gemm_bf16<<<dim3(32, 30), BDIM, 0, stream>>>(Xbf, Wcat, QKV, 4096, 3840,
                                                 1280);
  k_stats1<<<dim3(32, 8), 320, 0, stream>>>(QKV, psum, psq);
  k_stats2<<<dim3(5, 8), BDIM, 0, stream>>>(psum, psq, stats);
  k_adain_vt<<<11520, BDIM, 0, stream>>>(QKV, stats, qnb, knb, vtb);
  k_attn<<<dim3(8, 20, 12), BDIM, 0, stream>>>(qnb, knb, vtb, Opart, Lpart);
  k_combine<<<2560, BDIM, 0, stream>>>(Opart, Lpart, attnb);
  k_gemm_64x128<<<dim3(64, 10), BDIM, 0, stream>>>(attnb, Wobf, out, bo, 4096,
                                                   1280, 1280);
}

// Round 8
// 323.346 us; speedup vs baseline: 1.3133x; 1.3133x over previous
//
#include <hip/hip_runtime.h>
#include <math.h>

// ---------------------------------------------------------------------------
// SharedAttentionProcessor: B=4, H=20, S=1024, C=1280, hd=64
// R8: attention = R6's 64-key tiles (HBM locality: 124 MB fetch) + 32 KB LDS
// (K dbuf 16K + V single 8K + compact P 8K reused per 32-key chunk) ->
// 5 blocks/CU; R7's exact-floor P swizzle (b128 write, 2x b64 read);
// R5's two-barrier structure (occupancy beats barrier count).
// ---------------------------------------------------------------------------

typedef __bf16 bf16x8 __attribute__((ext_vector_type(8)));
typedef float f32x4 __attribute__((ext_vector_type(4)));
typedef unsigned short u16x8 __attribute__((ext_vector_type(8)));

#define BDIM 256

__device__ inline unsigned short f2bf(float f) {
  unsigned int u = __float_as_uint(f);
  u += 0x7fffu + ((u >> 16) & 1u);   // RNE (inputs finite)
  return (unsigned short)(u >> 16);
}
__device__ inline unsigned int pack_bf2(float lo, float hi) {
  return (unsigned int)f2bf(lo) | ((unsigned int)f2bf(hi) << 16);
}
__device__ inline float bf2f(unsigned short h) {
  return __uint_as_float(((unsigned int)h) << 16);
}

__device__ inline void gl_lds16(const unsigned short* g, unsigned short* l) {
  __builtin_amdgcn_global_load_lds(
      (const __attribute__((address_space(1))) unsigned int*)g,
      (__attribute__((address_space(3))) unsigned int*)l, 16, 0, 0);
}

// --------------------------- fused fp32 -> bf16 convert ---------------------
__global__ __launch_bounds__(BDIM) void k_convert_all(
    const float* __restrict__ X, const float* __restrict__ Wq,
    const float* __restrict__ Wk, const float* __restrict__ Wv,
    const float* __restrict__ Wo, unsigned short* __restrict__ Xbf,
    unsigned short* __restrict__ Wcat, unsigned short* __restrict__ Wobf) {
  const int idx = blockIdx.x * BDIM + threadIdx.x;
  const float* src;
  unsigned short* dst;
  int off;
  if (idx < 1310720) {
    src = X; dst = Xbf; off = idx;
  } else {
    const int r = idx - 1310720;
    const int which = r / 409600;
    off = r - which * 409600;
    src = (which == 0) ? Wq : (which == 1) ? Wk : (which == 2) ? Wv : Wo;
    dst = (which < 3) ? Wcat + (size_t)which * 1638400 : Wobf;
  }
  const float4 v = ((const float4*)src)[off];
  ushort4 o;
  o.x = f2bf(v.x); o.y = f2bf(v.y); o.z = f2bf(v.z); o.w = f2bf(v.w);
  ((ushort4*)dst)[off] = o;
}

// --------------------------- bf16 GEMM 128x128, BK=64 (QKV) -----------------
__global__ __launch_bounds__(BDIM) void k_gemm_bf16(
    const unsigned short* __restrict__ A, const unsigned short* __restrict__ B,
    unsigned short* __restrict__ Cbf, int M, int N, int K) {
  __shared__ unsigned short As[2][128 * 32];
  __shared__ unsigned short Bs[2][128 * 32];
  const int t = threadIdx.x;
  const int w = t >> 6, lane = t & 63, quad = lane >> 4, l16 = lane & 15;
  const int wm = (w >> 1) << 6, wn = (w & 1) << 6;
  const int mBase = blockIdx.x * 128, nBase = blockIdx.y * 128;

  f32x4 acc[4][4];
#pragma unroll
  for (int i = 0; i < 4; i++)
#pragma unroll
    for (int j = 0; j < 4; j++) acc[i][j] = (f32x4){0.f, 0.f, 0.f, 0.f};

  const int r0 = t >> 2;
  const int kk0 = (t & 3) * 8;

  for (int k0 = 0; k0 < K; k0 += 64) {
    const unsigned short* Ab = A + (size_t)(mBase + r0) * K + k0 + kk0;
    const unsigned short* Bb = B + (size_t)(nBase + r0) * K + k0 + kk0;
    gl_lds16(Ab, As[0] + t * 8);
    gl_lds16(Ab + (size_t)64 * K, As[0] + (t + 256) * 8);
    gl_lds16(Ab + 32, As[1] + t * 8);
    gl_lds16(Ab + (size_t)64 * K + 32, As[1] + (t + 256) * 8);
    gl_lds16(Bb, Bs[0] + t * 8);
    gl_lds16(Bb + (size_t)64 * K, Bs[0] + (t + 256) * 8);
    gl_lds16(Bb + 32, Bs[1] + t * 8);
    gl_lds16(Bb + (size_t)64 * K + 32, Bs[1] + (t + 256) * 8);
    __syncthreads();
    bf16x8 af[2][4], bfr[2][4];
#pragma unroll
    for (int hh = 0; hh < 2; hh++)
#pragma unroll
      for (int i = 0; i < 4; i++) {
        af[hh][i] = *(const bf16x8*)(As[hh] + (wm + i * 16 + l16) * 32 + quad * 8);
        bfr[hh][i] = *(const bf16x8*)(Bs[hh] + (wn + i * 16 + l16) * 32 + quad * 8);
      }
#pragma unroll
    for (int hh = 0; hh < 2; hh++)
#pragma unroll
      for (int mi = 0; mi < 4; mi++)
#pragma unroll
        for (int ni = 0; ni < 4; ni++)
          acc[mi][ni] = __builtin_amdgcn_mfma_f32_16x16x32_bf16(
              af[hh][mi], bfr[hh][ni], acc[mi][ni], 0, 0, 0);
    __syncthreads();
  }

#pragma unroll
  for (int mi = 0; mi < 4; mi++)
#pragma unroll
    for (int r = 0; r < 4; r++) {
      const int row = mBase + wm + mi * 16 + quad * 4 + r;
#pragma unroll
      for (int ni = 0; ni < 4; ni++)
        Cbf[(size_t)row * N + nBase + wn + ni * 16 + l16] = f2bf(acc[mi][ni][r]);
    }
}

// --------------------------- bf16 GEMM 64x128, BK=64 (out proj) -------------
__global__ __launch_bounds__(BDIM) void k_gemm_64x128(
    const unsigned short* __restrict__ A, const unsigned short* __restrict__ B,
    float* __restrict__ Cf, const float* __restrict__ bias, int M, int N,
    int K) {
  __shared__ unsigned short As[2][64 * 32];
  __shared__ unsigned short Bs[2][128 * 32];
  const int t = threadIdx.x;
  const int w = t >> 6, lane = t & 63, quad = lane >> 4, l16 = lane & 15;
  const int wm = (w >> 1) << 5, wn = (w & 1) << 6;
  const int mBase = blockIdx.x * 64, nBase = blockIdx.y * 128;

  f32x4 acc[2][4];
#pragma unroll
  for (int i = 0; i < 2; i++)
#pragma unroll
    for (int j = 0; j < 4; j++) acc[i][j] = (f32x4){0.f, 0.f, 0.f, 0.f};

  const int r0 = t >> 2;
  const int kk0 = (t & 3) * 8;

  for (int k0 = 0; k0 < K; k0 += 64) {
    const unsigned short* Ab = A + (size_t)(mBase + r0) * K + k0 + kk0;
    const unsigned short* Bb = B + (size_t)(nBase + r0) * K + k0 + kk0;
    gl_lds16(Ab, As[0] + t * 8);
    gl_lds16(Ab + 32, As[1] + t * 8);
    gl_lds16(Bb, Bs[0] + t * 8);
    gl_lds16(Bb + (size_t)64 * K, Bs[0] + (t + 256) * 8);
    gl_lds16(Bb + 32, Bs[1] + t * 8);
    gl_lds16(Bb + (size_t)64 * K + 32, Bs[1] + (t + 256) * 8);
    __syncthreads();
    bf16x8 af[2][2], bfr[2][4];
#pragma unroll
    for (int hh = 0; hh < 2; hh++) {
#pragma unroll
      for (int i = 0; i < 2; i++)
        af[hh][i] = *(const bf16x8*)(As[hh] + (wm + i * 16 + l16) * 32 + quad * 8);
#pragma unroll
      for (int i = 0; i < 4; i++)
        bfr[hh][i] = *(const bf16x8*)(Bs[hh] + (wn + i * 16 + l16) * 32 + quad * 8);
    }
#pragma unroll
    for (int hh = 0; hh < 2; hh++)
#pragma unroll
      for (int mi = 0; mi < 2; mi++)
#pragma unroll
        for (int ni = 0; ni < 4; ni++)
          acc[mi][ni] = __builtin_amdgcn_mfma_f32_16x16x32_bf16(
              af[hh][mi], bfr[hh][ni], acc[mi][ni], 0, 0, 0);
    __syncthreads();
  }

#pragma unroll
  for (int mi = 0; mi < 2; mi++)
#pragma unroll
    for (int r = 0; r < 4; r++) {
      const int row = mBase + wm + mi * 16 + quad * 4 + r;
#pragma unroll
      for (int ni = 0; ni < 4; ni++) {
        const int col = nBase + wn + ni * 16 + l16;
        Cf[(size_t)row * N + col] = acc[mi][ni][r] + bias[col];
      }
    }
}

// --------------------------- adain stats (two-stage) ------------------------
__global__ __launch_bounds__(320) void k_stats1(
    const unsigned short* __restrict__ QKV, float* __restrict__ psum,
    float* __restrict__ psq) {
  const int z = blockIdx.y, which = z >> 2, b = z & 3;
  const int c = threadIdx.x * 4;
  const size_t base =
      (size_t)(b * 1024 + blockIdx.x * 32) * 3840 + which * 1280 + c;
  float4 s = {0.f, 0.f, 0.f, 0.f}, s2 = {0.f, 0.f, 0.f, 0.f};
#pragma unroll 8
  for (int i = 0; i < 32; ++i) {
    const ushort4 xv = *(const ushort4*)(QKV + base + (size_t)i * 3840);
    const float x0 = bf2f(xv.x), x1 = bf2f(xv.y), x2 = bf2f(xv.z),
                x3 = bf2f(xv.w);
    s.x += x0; s.y += x1; s.z += x2; s.w += x3;
    s2.x = fmaf(x0, x0, s2.x); s2.y = fmaf(x1, x1, s2.y);
    s2.z = fmaf(x2, x2, s2.z); s2.w = fmaf(x3, x3, s2.w);
  }
  const size_t o = ((size_t)z * 32 + blockIdx.x) * 1280 + c;
  *(float4*)(psum + o) = s;
  *(float4*)(psq + o) = s2;
}

__global__ __launch_bounds__(BDIM) void k_stats2(
    const float* __restrict__ psum, const float* __restrict__ psq,
    float* __restrict__ stats) {
  const int z = blockIdx.y, which = z >> 2, b = z & 3;
  const int c = blockIdx.x * 256 + threadIdx.x;
  float s = 0.f, s2 = 0.f;
#pragma unroll
  for (int j = 0; j < 32; ++j) {
    s += psum[((size_t)z * 32 + j) * 1280 + c];
    s2 += psq[((size_t)z * 32 + j) * 1280 + c];
  }
  const float mean = s * (1.0f / 1024.0f);
  const float var = (s2 - 1024.0f * mean * mean) * (1.0f / 1023.0f);
  stats[((which * 2 + 0) * 4 + b) * 1280 + c] = mean;
  stats[((which * 2 + 1) * 4 + b) * 1280 + c] = sqrtf(var + 1e-5f);
}

// --------------------- adain apply + V transpose (merged) -------------------
__global__ __launch_bounds__(BDIM) void k_adain_vt(
    const unsigned short* __restrict__ QKV, const float* __restrict__ stats,
    unsigned short* __restrict__ qn, unsigned short* __restrict__ kn,
    unsigned short* __restrict__ vt) {
  __shared__ unsigned short tile[64][65];
  const int bx = blockIdx.x;
  if (bx < 10240) {
    const int which = bx / 5120;
    const int rem = bx - which * 5120;
    const int b = rem / 1280;
    const int xb = rem - b * 1280;
    const int idx = xb * BDIM + threadIdx.x;  // [0, 327680)
    const int s = idx / 320;
    const int c = (idx - s * 320) * 4;
    const int sb = (b < 2) ? 0 : 2;
    const ushort4 xv = *(const ushort4*)(QKV + ((size_t)(b * 1024 + s)) * 3840 +
                                         which * 1280 + c);
    const float4 mean =
        *(const float4*)(stats + ((which * 2 + 0) * 4 + b) * 1280 + c);
    const float4 stdv =
        *(const float4*)(stats + ((which * 2 + 1) * 4 + b) * 1280 + c);
    const float4 meanS =
        *(const float4*)(stats + ((which * 2 + 0) * 4 + sb) * 1280 + c);
    const float4 stdS =
        *(const float4*)(stats + ((which * 2 + 1) * 4 + sb) * 1280 + c);
    ushort4 o;
    o.x = f2bf((bf2f(xv.x) - mean.x) / stdv.x * stdS.x + meanS.x);
    o.y = f2bf((bf2f(xv.y) - mean.y) / stdv.y * stdS.y + meanS.y);
    o.z = f2bf((bf2f(xv.z) - mean.z) / stdv.z * stdS.z + meanS.z);
    o.w = f2bf((bf2f(xv.w) - mean.w) / stdv.w * stdS.w + meanS.w);
    unsigned short* dst = (which == 0) ? qn : kn;
    *(ushort4*)(dst + ((size_t)(b * 1024 + s)) * 1280 + c) = o;
  } else {
    const int tb = bx - 10240;           // [0,1280)
    const int b = tb / 320;
    const int r2 = tb - b * 320;
    const int c0 = (r2 / 16) * 64;
    const int s0 = (r2 & 15) * 64;
    const int t = threadIdx.x;
    const int r = t >> 2, seg = (t & 3) * 16;
    const size_t goff = ((size_t)(b * 1024 + s0 + r)) * 3840 + 2560 + c0 + seg;
    const u16x8 va = *(const u16x8*)(QKV + goff);
    const u16x8 vb = *(const u16x8*)(QKV + goff + 8);
#pragma unroll
    for (int j = 0; j < 8; j++) {
      tile[r][seg + j] = va[j];
      tile[r][seg + 8 + j] = vb[j];
    }
    __syncthreads();
    u16x8 o0, o1;
#pragma unroll
    for (int j = 0; j < 8; j++) {
      o0[j] = tile[seg + j][r];
      o1[j] = tile[seg + 8 + j][r];
    }
    const size_t ooff = ((size_t)(b * 1280 + c0 + r)) * 1024 + s0 + seg;
    *(u16x8*)(vt + ooff) = o0;
    *(u16x8*)(vt + ooff + 8) = o1;
  }
}

// --------------------------- flash attention --------------------------------
// grid (8, 20, 12): z -> (b, chunk); each block: 8 iterations of 64 keys.
// LDS 32 KB -> 5 blocks/CU: Ks dbuf 16K, Vs single 8K, Plds 8K (compact,
// reused for each 32-key PV chunk; per-wave LDS ordering makes that safe).
// Two barriers per iteration (sync1: K ready / V-reads done; sync2: V ready).
// P transform at exact LDS data floor (R7-verified):
//   write: one b128/lane/g/chunk at granule quad^(l16&3)
//   read:  two b64/lane/g/chunk (writer quads (2q)&3,(2q+1)&3, half = q>>1)
__global__ __launch_bounds__(BDIM, 5) void k_attn(
    const unsigned short* __restrict__ qn, const unsigned short* __restrict__ kn,
    const unsigned short* __restrict__ vt, unsigned short* __restrict__ Opart,
    float* __restrict__ Lpart) {
  const int S = 1024, C = 1280;
  const int qt = blockIdx.x, h = blockIdx.y, zs = blockIdx.z;
  int b, chunk;
  if (zs < 2)      { b = 0; chunk = zs; }
  else if (zs < 6) { b = 1; chunk = zs - 2; }
  else if (zs < 8) { b = 2; chunk = zs - 6; }
  else             { b = 3; chunk = zs - 8; }
  const int ktBeg = chunk * 8;
  const int t = threadIdx.x, w = t >> 6, lane = t & 63;
  const int quad = lane >> 4, l16 = lane & 15;
  const int bstyle = (b < 2) ? 0 : 2;
  const int qrow = qt * 128 + w * 32;

  __shared__ unsigned short Ks[2][2][64 * 32];  // [buf][dim-half] 16 KB
  __shared__ unsigned short Vs[2][64 * 32];     // [key-half]       8 KB
  __shared__ unsigned short Plds[4][32][32];    // compact, swizzled 8 KB

  bf16x8 aq[2][2];
#pragma unroll
  for (int g = 0; g < 2; ++g) {
    const size_t qoff =
        ((size_t)(b * S + qrow + g * 16 + l16)) * C + h * 64 + quad * 8;
    aq[g][0] = *(const bf16x8*)(qn + qoff);
    aq[g][1] = *(const bf16x8*)(qn + qoff + 32);
  }

  bf16x8 ones;
#pragma unroll
  for (int i = 0; i < 8; ++i) ones[i] = (__bf16)1.0f;

  f32x4 o[2][4], lsum[2];
#pragma unroll
  for (int g = 0; g < 2; ++g) {
    lsum[g] = (f32x4){0.f, 0.f, 0.f, 0.f};
#pragma unroll
    for (int i = 0; i < 4; i++) o[g][i] = (f32x4){0.f, 0.f, 0.f, 0.f};
  }

  const int krow = t >> 2;           // 0..63
  const int kseg = (t & 3) * 8;      // 0,8,16,24

  auto stageK = [&](int buf, int kt) {
    const int bs = (kt < 16) ? b : bstyle;
    const int sk = (kt & 15) * 64;
    const unsigned short* kg =
        kn + (size_t)(bs * S + sk + krow) * C + h * 64 + kseg;
    gl_lds16(kg, Ks[buf][0] + t * 8);
    gl_lds16(kg + 32, Ks[buf][1] + t * 8);
  };
  auto stageV = [&](int kt) {
    const int bs = (kt < 16) ? b : bstyle;
    const int sk = (kt & 15) * 64;
    const unsigned short* vg =
        vt + (size_t)(bs * C + h * 64 + krow) * S + sk + kseg;
    gl_lds16(vg, Vs[0] + t * 8);
    gl_lds16(vg + 32, Vs[1] + t * 8);
  };

  stageK(0, ktBeg);

  const float SCALE2 = 0.125f * 1.44269504088896341f;
  const int swz = l16 & 3;
  const int h_ = quad >> 1;
  const int qw0 = (2 * quad) & 3, qw1 = (2 * quad + 1) & 3;

  for (int i = 0; i < 8; ++i) {
    const int kt = ktBeg + i;
    const int buf = i & 1;
    __syncthreads();  // K[buf] landed; all reads of Vs from prev iter done
    stageV(kt);
    if (i + 1 < 8) stageK(buf ^ 1, kt + 1);

    const float bias2 = (kt >= 16) ? 1.0f : 0.0f;

    // S^T: D[m=key nt*16+quad*4+r][n=query l16], nt=0..3 (64 keys)
    f32x4 z2[2][4];
#pragma unroll
    for (int nt = 0; nt < 4; ++nt) {
      const bf16x8 bk0 =
          *(const bf16x8*)(Ks[buf][0] + (nt * 16 + l16) * 32 + quad * 8);
      const bf16x8 bk1 =
          *(const bf16x8*)(Ks[buf][1] + (nt * 16 + l16) * 32 + quad * 8);
#pragma unroll
      for (int g = 0; g < 2; ++g) {
        f32x4 zz = (f32x4){0.f, 0.f, 0.f, 0.f};
        zz = __builtin_amdgcn_mfma_f32_16x16x32_bf16(bk0, aq[g][0], zz, 0, 0, 0);
        zz = __builtin_amdgcn_mfma_f32_16x16x32_bf16(bk1, aq[g][1], zz, 0, 0, 0);
        z2[g][nt] = zz;
      }
    }

    // P transform per 32-key chunk c (keys 32c..32c+31 = z2[2c], z2[2c+1]):
    // write one b128, read two b64 -> pa[g][c] (A-frag keys 32c+quad*8+j)
    bf16x8 pa[2][2];
#pragma unroll
    for (int c = 0; c < 2; ++c) {
#pragma unroll
      for (int g = 0; g < 2; ++g) {
        uint4 pk;
        {
          const float e0 = exp2f(fmaf(z2[g][2 * c][0], SCALE2, bias2));
          const float e1 = exp2f(fmaf(z2[g][2 * c][1], SCALE2, bias2));
          const float e2 = exp2f(fmaf(z2[g][2 * c][2], SCALE2, bias2));
          const float e3 = exp2f(fmaf(z2[g][2 * c][3], SCALE2, bias2));
          pk.x = pack_bf2(e0, e1);
          pk.y = pack_bf2(e2, e3);
        }
        {
          const float e0 = exp2f(fmaf(z2[g][2 * c + 1][0], SCALE2, bias2));
          const float e1 = exp2f(fmaf(z2[g][2 * c + 1][1], SCALE2, bias2));
          const float e2 = exp2f(fmaf(z2[g][2 * c + 1][2], SCALE2, bias2));
          const float e3 = exp2f(fmaf(z2[g][2 * c + 1][3], SCALE2, bias2));
          pk.z = pack_bf2(e0, e1);
          pk.w = pack_bf2(e2, e3);
        }
        *(uint4*)(&Plds[w][g * 16 + l16][(quad ^ swz) * 8]) = pk;
      }
      // reads must follow all writes of this chunk (cross-quad gather);
      // same-wave LDS ops are ordered, both loops are over this wave only.
#pragma unroll
      for (int g = 0; g < 2; ++g) {
        const uint2 lo =
            *(const uint2*)(&Plds[w][g * 16 + l16][(qw0 ^ swz) * 8 + h_ * 4]);
        const uint2 hi =
            *(const uint2*)(&Plds[w][g * 16 + l16][(qw1 ^ swz) * 8 + h_ * 4]);
        union { unsigned int u[4]; bf16x8 v; } pu;
        pu.u[0] = lo.x; pu.u[1] = lo.y; pu.u[2] = hi.x; pu.u[3] = hi.y;
        pa[g][c] = pu.v;
        lsum[g] = __builtin_amdgcn_mfma_f32_16x16x32_bf16(pa[g][c], ones,
                                                          lsum[g], 0, 0, 0);
      }
    }

    __syncthreads();  // V staged

    // O += P_c x V_c (V chunk c = keys 32c..32c+31)
#pragma unroll
    for (int c = 0; c < 2; ++c)
#pragma unroll
      for (int g = 0; g < 2; ++g)
#pragma unroll
        for (int dt = 0; dt < 4; ++dt) {
          const bf16x8 vb =
              *(const bf16x8*)(Vs[c] + (dt * 16 + l16) * 32 + quad * 8);
          o[g][dt] = __builtin_amdgcn_mfma_f32_16x16x32_bf16(pa[g][c], vb,
                                                             o[g][dt], 0, 0, 0);
        }
  }

  if (l16 == 0) {
#pragma unroll
    for (int g = 0; g < 2; ++g)
#pragma unroll
      for (int r = 0; r < 4; ++r)
        Lpart[((size_t)zs * 20 + h) * 1024 + qrow + g * 16 + quad * 4 + r] =
            lsum[g][r];
  }

  unsigned short* Op = Opart + (size_t)zs * 1024 * 1280;
#pragma unroll
  for (int g = 0; g < 2; ++g)
#pragma unroll
    for (int dt = 0; dt < 4; ++dt)
#pragma unroll
      for (int r = 0; r < 4; ++r)
        Op[(size_t)(qrow + g * 16 + quad * 4 + r) * 1280 + h * 64 + dt * 16 +
           l16] = f2bf(o[g][dt][r]);
}

// --------------------------- combine slice partials -------------------------
__global__ __launch_bounds__(BDIM) void k_combine(
    const unsigned short* __restrict__ Opart, const float* __restrict__ Lpart,
    unsigned short* __restrict__ attnb) {
  const int idx = blockIdx.x * BDIM + threadIdx.x;  // [0, 655360)
  const int row = idx / 160;
  const int c = (idx - row * 160) * 8;
  const int b = row >> 10, q = row & 1023, h = c >> 6;
  const int zb = (b >> 1) * 6 + (b & 1) * 2;  // 0,2,6,8
  const int ns = 2 + (b & 1) * 2;             // 2 or 4 slices
  float L = 0.f;
  float acc[8] = {0.f, 0.f, 0.f, 0.f, 0.f, 0.f, 0.f, 0.f};
  for (int s = 0; s < ns; ++s) {
    L += Lpart[((size_t)(zb + s) * 20 + h) * 1024 + q];
    const u16x8 v =
        *(const u16x8*)(Opart + (size_t)(zb + s) * 1310720 + (size_t)q * 1280 + c);
#pragma unroll
    for (int j = 0; j < 8; ++j) acc[j] += bf2f(v[j]);
  }
  const float rl = 1.0f / L;
  u16x8 o8;
#pragma unroll
  for (int j = 0; j < 8; ++j) o8[j] = f2bf(acc[j] * rl);
  *(u16x8*)(attnb + (size_t)row * 1280 + c) = o8;
}

// ---------------------------------------------------------------------------
extern "C" void kernel_launch(void* const* d_in, const int* in_sizes, int n_in,
                              void* d_out, int out_size, void* d_ws,
                              size_t ws_size, hipStream_t stream) {
  const float* X = (const float*)d_in[0];
  const float* Wq = (const float*)d_in[1];
  const float* Wk = (const float*)d_in[2];
  const float* Wv = (const float*)d_in[3];
  const float* Wo = (const float*)d_in[4];
  const float* bo = (const float*)d_in[5];
  float* out = (float*)d_out;

  char* ws = (char*)d_ws;
  size_t off = 0;
  auto alloc = [&](size_t bytes) {
    char* p = ws + off;
    off += (bytes + 255) & ~(size_t)255;
    return p;
  };
  unsigned short* Wcat = (unsigned short*)alloc(3840ull * 1280 * 2);
  unsigned short* Xbf = (unsigned short*)alloc(4096ull * 1280 * 2);
  unsigned short* QKV = (unsigned short*)alloc(4096ull * 3840 * 2);
  unsigned short* Wobf = (unsigned short*)alloc(1280ull * 1280 * 2);
  float* stats = (float*)alloc(2ull * 2 * 4 * 1280 * 4);
  unsigned short* qnb = (unsigned short*)alloc(4096ull * 1280 * 2);
  unsigned short* knb = (unsigned short*)alloc(4096ull * 1280 * 2);
  unsigned short* vtb = (unsigned short*)alloc(4096ull * 1280 * 2);
  unsigned short* attnb = (unsigned short*)alloc(4096ull * 1280 * 2);

  unsigned short* Opart = QKV;                        // 12 x 1024 x 1280 bf16
  float* Lpart = (float*)Wcat;                        // 12 x 20 x 1024 fp32
  float* psum = (float*)attnb;                        // 8 x 32 x 1280 fp32
  float* psq = (float*)(attnb + 4096ull * 1280 / 2);  // second half

  k_convert_all<<<11520, BDIM, 0, stream>>>(X, Wq, Wk, Wv, Wo, Xbf, Wcat, Wobf);
  k_gemm_bf16<<<dim3(32, 30), BDIM, 0, stream>>>(Xbf, Wcat, QKV, 4096, 3840,
                                                 1280);
  k_stats1<<<dim3(32, 8), 320, 0, stream>>>(QKV, psum, psq);
  k_stats2<<<dim3(5, 8), BDIM, 0, stream>>>(psum, psq, stats);
  k_adain_vt<<<11520, BDIM, 0, stream>>>(QKV, stats, qnb, knb, vtb);
  k_attn<<<dim3(8, 20, 12), BDIM, 0, stream>>>(qnb, knb, vtb, Opart, Lpart);
  k_combine<<<2560, BDIM, 0, stream>>>(Opart, Lpart, attnb);
  k_gemm_64x128<<<dim3(64, 10), BDIM, 0, stream>>>(attnb, Wobf, out, bo, 4096,
                                                   1280, 1280);
}

// Round 9
// 284.400 us; speedup vs baseline: 1.4932x; 1.1369x over previous
//
#include <hip/hip_runtime.h>
#include <math.h>

// ---------------------------------------------------------------------------
// SharedAttentionProcessor: B=4, H=20, S=1024, C=1280, hd=64
// R9: attention back to R5's proven structure (Ks dbuf 16K + Vs single 8K +
// Plds 16K, two barriers, 4 blk/CU) + XCD-locality remap: the 8 qt-blocks
// sharing one (h,zs) K/V slice get ids spaced by 8 -> same XCD -> K/V stays
// L2-resident (R8 lesson: attention was fabric-bound, FETCH 183 MB).
// ---------------------------------------------------------------------------

typedef __bf16 bf16x8 __attribute__((ext_vector_type(8)));
typedef float f32x4 __attribute__((ext_vector_type(4)));
typedef unsigned short u16x8 __attribute__((ext_vector_type(8)));

#define BDIM 256

__device__ inline unsigned short f2bf(float f) {
  unsigned int u = __float_as_uint(f);
  u += 0x7fffu + ((u >> 16) & 1u);   // RNE (inputs finite)
  return (unsigned short)(u >> 16);
}
__device__ inline unsigned int pack_bf2(float lo, float hi) {
  return (unsigned int)f2bf(lo) | ((unsigned int)f2bf(hi) << 16);
}
__device__ inline float bf2f(unsigned short h) {
  return __uint_as_float(((unsigned int)h) << 16);
}

__device__ inline void gl_lds16(const unsigned short* g, unsigned short* l) {
  __builtin_amdgcn_global_load_lds(
      (const __attribute__((address_space(1))) unsigned int*)g,
      (__attribute__((address_space(3))) unsigned int*)l, 16, 0, 0);
}

// --------------------------- fused fp32 -> bf16 convert ---------------------
__global__ __launch_bounds__(BDIM) void k_convert_all(
    const float* __restrict__ X, const float* __restrict__ Wq,
    const float* __restrict__ Wk, const float* __restrict__ Wv,
    const float* __restrict__ Wo, unsigned short* __restrict__ Xbf,
    unsigned short* __restrict__ Wcat, unsigned short* __restrict__ Wobf) {
  const int idx = blockIdx.x * BDIM + threadIdx.x;
  const float* src;
  unsigned short* dst;
  int off;
  if (idx < 1310720) {
    src = X; dst = Xbf; off = idx;
  } else {
    const int r = idx - 1310720;
    const int which = r / 409600;
    off = r - which * 409600;
    src = (which == 0) ? Wq : (which == 1) ? Wk : (which == 2) ? Wv : Wo;
    dst = (which < 3) ? Wcat + (size_t)which * 1638400 : Wobf;
  }
  const float4 v = ((const float4*)src)[off];
  ushort4 o;
  o.x = f2bf(v.x); o.y = f2bf(v.y); o.z = f2bf(v.z); o.w = f2bf(v.w);
  ((ushort4*)dst)[off] = o;
}

// --------------------------- bf16 GEMM 128x128, BK=64 (QKV) -----------------
__global__ __launch_bounds__(BDIM) void k_gemm_bf16(
    const unsigned short* __restrict__ A, const unsigned short* __restrict__ B,
    unsigned short* __restrict__ Cbf, int M, int N, int K) {
  __shared__ unsigned short As[2][128 * 32];
  __shared__ unsigned short Bs[2][128 * 32];
  const int t = threadIdx.x;
  const int w = t >> 6, lane = t & 63, quad = lane >> 4, l16 = lane & 15;
  const int wm = (w >> 1) << 6, wn = (w & 1) << 6;
  const int mBase = blockIdx.x * 128, nBase = blockIdx.y * 128;

  f32x4 acc[4][4];
#pragma unroll
  for (int i = 0; i < 4; i++)
#pragma unroll
    for (int j = 0; j < 4; j++) acc[i][j] = (f32x4){0.f, 0.f, 0.f, 0.f};

  const int r0 = t >> 2;
  const int kk0 = (t & 3) * 8;

  for (int k0 = 0; k0 < K; k0 += 64) {
    const unsigned short* Ab = A + (size_t)(mBase + r0) * K + k0 + kk0;
    const unsigned short* Bb = B + (size_t)(nBase + r0) * K + k0 + kk0;
    gl_lds16(Ab, As[0] + t * 8);
    gl_lds16(Ab + (size_t)64 * K, As[0] + (t + 256) * 8);
    gl_lds16(Ab + 32, As[1] + t * 8);
    gl_lds16(Ab + (size_t)64 * K + 32, As[1] + (t + 256) * 8);
    gl_lds16(Bb, Bs[0] + t * 8);
    gl_lds16(Bb + (size_t)64 * K, Bs[0] + (t + 256) * 8);
    gl_lds16(Bb + 32, Bs[1] + t * 8);
    gl_lds16(Bb + (size_t)64 * K + 32, Bs[1] + (t + 256) * 8);
    __syncthreads();
    bf16x8 af[2][4], bfr[2][4];
#pragma unroll
    for (int hh = 0; hh < 2; hh++)
#pragma unroll
      for (int i = 0; i < 4; i++) {
        af[hh][i] = *(const bf16x8*)(As[hh] + (wm + i * 16 + l16) * 32 + quad * 8);
        bfr[hh][i] = *(const bf16x8*)(Bs[hh] + (wn + i * 16 + l16) * 32 + quad * 8);
      }
#pragma unroll
    for (int hh = 0; hh < 2; hh++)
#pragma unroll
      for (int mi = 0; mi < 4; mi++)
#pragma unroll
        for (int ni = 0; ni < 4; ni++)
          acc[mi][ni] = __builtin_amdgcn_mfma_f32_16x16x32_bf16(
              af[hh][mi], bfr[hh][ni], acc[mi][ni], 0, 0, 0);
    __syncthreads();
  }

#pragma unroll
  for (int mi = 0; mi < 4; mi++)
#pragma unroll
    for (int r = 0; r < 4; r++) {
      const int row = mBase + wm + mi * 16 + quad * 4 + r;
#pragma unroll
      for (int ni = 0; ni < 4; ni++)
        Cbf[(size_t)row * N + nBase + wn + ni * 16 + l16] = f2bf(acc[mi][ni][r]);
    }
}

// --------------------------- bf16 GEMM 64x128, BK=64 (out proj) -------------
__global__ __launch_bounds__(BDIM) void k_gemm_64x128(
    const unsigned short* __restrict__ A, const unsigned short* __restrict__ B,
    float* __restrict__ Cf, const float* __restrict__ bias, int M, int N,
    int K) {
  __shared__ unsigned short As[2][64 * 32];
  __shared__ unsigned short Bs[2][128 * 32];
  const int t = threadIdx.x;
  const int w = t >> 6, lane = t & 63, quad = lane >> 4, l16 = lane & 15;
  const int wm = (w >> 1) << 5, wn = (w & 1) << 6;
  const int mBase = blockIdx.x * 64, nBase = blockIdx.y * 128;

  f32x4 acc[2][4];
#pragma unroll
  for (int i = 0; i < 2; i++)
#pragma unroll
    for (int j = 0; j < 4; j++) acc[i][j] = (f32x4){0.f, 0.f, 0.f, 0.f};

  const int r0 = t >> 2;
  const int kk0 = (t & 3) * 8;

  for (int k0 = 0; k0 < K; k0 += 64) {
    const unsigned short* Ab = A + (size_t)(mBase + r0) * K + k0 + kk0;
    const unsigned short* Bb = B + (size_t)(nBase + r0) * K + k0 + kk0;
    gl_lds16(Ab, As[0] + t * 8);
    gl_lds16(Ab + 32, As[1] + t * 8);
    gl_lds16(Bb, Bs[0] + t * 8);
    gl_lds16(Bb + (size_t)64 * K, Bs[0] + (t + 256) * 8);
    gl_lds16(Bb + 32, Bs[1] + t * 8);
    gl_lds16(Bb + (size_t)64 * K + 32, Bs[1] + (t + 256) * 8);
    __syncthreads();
    bf16x8 af[2][2], bfr[2][4];
#pragma unroll
    for (int hh = 0; hh < 2; hh++) {
#pragma unroll
      for (int i = 0; i < 2; i++)
        af[hh][i] = *(const bf16x8*)(As[hh] + (wm + i * 16 + l16) * 32 + quad * 8);
#pragma unroll
      for (int i = 0; i < 4; i++)
        bfr[hh][i] = *(const bf16x8*)(Bs[hh] + (wn + i * 16 + l16) * 32 + quad * 8);
    }
#pragma unroll
    for (int hh = 0; hh < 2; hh++)
#pragma unroll
      for (int mi = 0; mi < 2; mi++)
#pragma unroll
        for (int ni = 0; ni < 4; ni++)
          acc[mi][ni] = __builtin_amdgcn_mfma_f32_16x16x32_bf16(
              af[hh][mi], bfr[hh][ni], acc[mi][ni], 0, 0, 0);
    __syncthreads();
  }

#pragma unroll
  for (int mi = 0; mi < 2; mi++)
#pragma unroll
    for (int r = 0; r < 4; r++) {
      const int row = mBase + wm + mi * 16 + quad * 4 + r;
#pragma unroll
      for (int ni = 0; ni < 4; ni++) {
        const int col = nBase + wn + ni * 16 + l16;
        Cf[(size_t)row * N + col] = acc[mi][ni][r] + bias[col];
      }
    }
}

// --------------------------- adain stats (two-stage) ------------------------
__global__ __launch_bounds__(320) void k_stats1(
    const unsigned short* __restrict__ QKV, float* __restrict__ psum,
    float* __restrict__ psq) {
  const int z = blockIdx.y, which = z >> 2, b = z & 3;
  const int c = threadIdx.x * 4;
  const size_t base =
      (size_t)(b * 1024 + blockIdx.x * 32) * 3840 + which * 1280 + c;
  float4 s = {0.f, 0.f, 0.f, 0.f}, s2 = {0.f, 0.f, 0.f, 0.f};
#pragma unroll 8
  for (int i = 0; i < 32; ++i) {
    const ushort4 xv = *(const ushort4*)(QKV + base + (size_t)i * 3840);
    const float x0 = bf2f(xv.x), x1 = bf2f(xv.y), x2 = bf2f(xv.z),
                x3 = bf2f(xv.w);
    s.x += x0; s.y += x1; s.z += x2; s.w += x3;
    s2.x = fmaf(x0, x0, s2.x); s2.y = fmaf(x1, x1, s2.y);
    s2.z = fmaf(x2, x2, s2.z); s2.w = fmaf(x3, x3, s2.w);
  }
  const size_t o = ((size_t)z * 32 + blockIdx.x) * 1280 + c;
  *(float4*)(psum + o) = s;
  *(float4*)(psq + o) = s2;
}

__global__ __launch_bounds__(BDIM) void k_stats2(
    const float* __restrict__ psum, const float* __restrict__ psq,
    float* __restrict__ stats) {
  const int z = blockIdx.y, which = z >> 2, b = z & 3;
  const int c = blockIdx.x * 256 + threadIdx.x;
  float s = 0.f, s2 = 0.f;
#pragma unroll
  for (int j = 0; j < 32; ++j) {
    s += psum[((size_t)z * 32 + j) * 1280 + c];
    s2 += psq[((size_t)z * 32 + j) * 1280 + c];
  }
  const float mean = s * (1.0f / 1024.0f);
  const float var = (s2 - 1024.0f * mean * mean) * (1.0f / 1023.0f);
  stats[((which * 2 + 0) * 4 + b) * 1280 + c] = mean;
  stats[((which * 2 + 1) * 4 + b) * 1280 + c] = sqrtf(var + 1e-5f);
}

// --------------------- adain apply + V transpose (merged) -------------------
__global__ __launch_bounds__(BDIM) void k_adain_vt(
    const unsigned short* __restrict__ QKV, const float* __restrict__ stats,
    unsigned short* __restrict__ qn, unsigned short* __restrict__ kn,
    unsigned short* __restrict__ vt) {
  __shared__ unsigned short tile[64][65];
  const int bx = blockIdx.x;
  if (bx < 10240) {
    const int which = bx / 5120;
    const int rem = bx - which * 5120;
    const int b = rem / 1280;
    const int xb = rem - b * 1280;
    const int idx = xb * BDIM + threadIdx.x;  // [0, 327680)
    const int s = idx / 320;
    const int c = (idx - s * 320) * 4;
    const int sb = (b < 2) ? 0 : 2;
    const ushort4 xv = *(const ushort4*)(QKV + ((size_t)(b * 1024 + s)) * 3840 +
                                         which * 1280 + c);
    const float4 mean =
        *(const float4*)(stats + ((which * 2 + 0) * 4 + b) * 1280 + c);
    const float4 stdv =
        *(const float4*)(stats + ((which * 2 + 1) * 4 + b) * 1280 + c);
    const float4 meanS =
        *(const float4*)(stats + ((which * 2 + 0) * 4 + sb) * 1280 + c);
    const float4 stdS =
        *(const float4*)(stats + ((which * 2 + 1) * 4 + sb) * 1280 + c);
    ushort4 o;
    o.x = f2bf((bf2f(xv.x) - mean.x) / stdv.x * stdS.x + meanS.x);
    o.y = f2bf((bf2f(xv.y) - mean.y) / stdv.y * stdS.y + meanS.y);
    o.z = f2bf((bf2f(xv.z) - mean.z) / stdv.z * stdS.z + meanS.z);
    o.w = f2bf((bf2f(xv.w) - mean.w) / stdv.w * stdS.w + meanS.w);
    unsigned short* dst = (which == 0) ? qn : kn;
    *(ushort4*)(dst + ((size_t)(b * 1024 + s)) * 1280 + c) = o;
  } else {
    const int tb = bx - 10240;           // [0,1280)
    const int b = tb / 320;
    const int r2 = tb - b * 320;
    const int c0 = (r2 / 16) * 64;
    const int s0 = (r2 & 15) * 64;
    const int t = threadIdx.x;
    const int r = t >> 2, seg = (t & 3) * 16;
    const size_t goff = ((size_t)(b * 1024 + s0 + r)) * 3840 + 2560 + c0 + seg;
    const u16x8 va = *(const u16x8*)(QKV + goff);
    const u16x8 vb = *(const u16x8*)(QKV + goff + 8);
#pragma unroll
    for (int j = 0; j < 8; j++) {
      tile[r][seg + j] = va[j];
      tile[r][seg + 8 + j] = vb[j];
    }
    __syncthreads();
    u16x8 o0, o1;
#pragma unroll
    for (int j = 0; j < 8; j++) {
      o0[j] = tile[seg + j][r];
      o1[j] = tile[seg + 8 + j][r];
    }
    const size_t ooff = ((size_t)(b * 1280 + c0 + r)) * 1024 + s0 + seg;
    *(u16x8*)(vt + ooff) = o0;
    *(u16x8*)(vt + ooff + 8) = o1;
  }
}

// --------------------------- flash attention --------------------------------
// grid (8, 20, 12) = 1920 blocks, 8 iterations x 64 keys each.
// XCD remap: L = bx + 8*(by + 20*bz); qt = (L>>3)&7; (h,zs) from
// (L&7) + 8*(L>>6). The 8 qt-blocks sharing a K/V slice are spaced by 8 in
// dispatch id -> same XCD (%8 heuristic) -> slice stays L2-resident.
// LDS 40 KB (4 blk/CU): Ks dbuf 16K, Vs single 8K (staged under QK+exp),
// Plds 16K XOR-swizzled (R5-proven). Two barriers per iteration.
__global__ __launch_bounds__(BDIM, 4) void k_attn(
    const unsigned short* __restrict__ qn, const unsigned short* __restrict__ kn,
    const unsigned short* __restrict__ vt, unsigned short* __restrict__ Opart,
    float* __restrict__ Lpart) {
  const int S = 1024, C = 1280;
  const int L = blockIdx.x + 8 * (blockIdx.y + 20 * blockIdx.z);
  const int qt = (L >> 3) & 7;
  const int hz = (L & 7) + ((L >> 6) << 3);  // 0..239
  const int h = hz % 20;
  const int zs = hz / 20;
  int b, chunk;
  if (zs < 2)      { b = 0; chunk = zs; }
  else if (zs < 6) { b = 1; chunk = zs - 2; }
  else if (zs < 8) { b = 2; chunk = zs - 6; }
  else             { b = 3; chunk = zs - 8; }
  const int ktBeg = chunk * 8;
  const int t = threadIdx.x, w = t >> 6, lane = t & 63;
  const int quad = lane >> 4, l16 = lane & 15;
  const int bstyle = (b < 2) ? 0 : 2;
  const int qrow = qt * 128 + w * 32;

  __shared__ unsigned short Ks[2][2][64 * 32];  // [buf][dim-half] 16 KB
  __shared__ unsigned short Vs[2][64 * 32];     // [key-half]       8 KB
  __shared__ unsigned short Plds[4][32][64];    // XOR-swizzled    16 KB

  bf16x8 aq[2][2];
#pragma unroll
  for (int g = 0; g < 2; ++g) {
    const size_t qoff =
        ((size_t)(b * S + qrow + g * 16 + l16)) * C + h * 64 + quad * 8;
    aq[g][0] = *(const bf16x8*)(qn + qoff);
    aq[g][1] = *(const bf16x8*)(qn + qoff + 32);
  }

  bf16x8 ones;
#pragma unroll
  for (int i = 0; i < 8; ++i) ones[i] = (__bf16)1.0f;

  f32x4 o[2][4], lsum[2];
#pragma unroll
  for (int g = 0; g < 2; ++g) {
    lsum[g] = (f32x4){0.f, 0.f, 0.f, 0.f};
#pragma unroll
    for (int i = 0; i < 4; i++) o[g][i] = (f32x4){0.f, 0.f, 0.f, 0.f};
  }

  const int krow = t >> 2;
  const int kseg = (t & 3) * 8;
  const int sw = l16 & 14;  // P-granule XOR swizzle (bit0 clear -> b128 ok)

  auto stageK = [&](int buf, int kt) {
    const int bs = (kt < 16) ? b : bstyle;
    const int sk = (kt & 15) * 64;
    const unsigned short* kg =
        kn + (size_t)(bs * S + sk + krow) * C + h * 64 + kseg;
    gl_lds16(kg, Ks[buf][0] + t * 8);
    gl_lds16(kg + 32, Ks[buf][1] + t * 8);
  };
  auto stageV = [&](int kt) {
    const int bs = (kt < 16) ? b : bstyle;
    const int sk = (kt & 15) * 64;
    const unsigned short* vg =
        vt + (size_t)(bs * C + h * 64 + krow) * S + sk + kseg;
    gl_lds16(vg, Vs[0] + t * 8);
    gl_lds16(vg + 32, Vs[1] + t * 8);
  };

  stageK(0, ktBeg);

  const float SCALE2 = 0.125f * 1.44269504088896341f;

  for (int i = 0; i < 8; ++i) {
    const int kt = ktBeg + i;
    const int buf = i & 1;
    __syncthreads();  // K[buf] staged; prior V reads done
    stageV(kt);
    if (i + 1 < 8) stageK(buf ^ 1, kt + 1);

    const float bias2 = (kt >= 16) ? 1.0f : 0.0f;

    // S^T: D[m=key (nt*16+quad*4+r)][n=query l16]
    f32x4 z2[2][4];
#pragma unroll
    for (int nt = 0; nt < 4; ++nt) {
      const bf16x8 bk0 =
          *(const bf16x8*)(Ks[buf][0] + (nt * 16 + l16) * 32 + quad * 8);
      const bf16x8 bk1 =
          *(const bf16x8*)(Ks[buf][1] + (nt * 16 + l16) * 32 + quad * 8);
#pragma unroll
      for (int g = 0; g < 2; ++g) {
        f32x4 zz = (f32x4){0.f, 0.f, 0.f, 0.f};
        zz = __builtin_amdgcn_mfma_f32_16x16x32_bf16(bk0, aq[g][0], zz, 0, 0, 0);
        zz = __builtin_amdgcn_mfma_f32_16x16x32_bf16(bk1, aq[g][1], zz, 0, 0, 0);
        z2[g][nt] = zz;
      }
    }

    // exp2, pack 4 keys -> one swizzled b64 write
#pragma unroll
    for (int g = 0; g < 2; ++g) {
#pragma unroll
      for (int nt = 0; nt < 4; ++nt) {
        const float e0 = exp2f(fmaf(z2[g][nt][0], SCALE2, bias2));
        const float e1 = exp2f(fmaf(z2[g][nt][1], SCALE2, bias2));
        const float e2 = exp2f(fmaf(z2[g][nt][2], SCALE2, bias2));
        const float e3 = exp2f(fmaf(z2[g][nt][3], SCALE2, bias2));
        uint2 pk;
        pk.x = pack_bf2(e0, e1);
        pk.y = pack_bf2(e2, e3);
        const int phys = (nt * 4 + quad) ^ sw;
        *(uint2*)(&Plds[w][g * 16 + l16][phys * 4]) = pk;
      }
    }

    __syncthreads();  // V staged

    // lsum += P*1 ; O += P*V^T
#pragma unroll
    for (int g = 0; g < 2; ++g) {
      const int a0 = (2 * quad) ^ sw;
      const int a1 = (2 * quad + 8) ^ sw;
      const bf16x8 pa0 = *(const bf16x8*)(&Plds[w][g * 16 + l16][a0 * 4]);
      const bf16x8 pa1 = *(const bf16x8*)(&Plds[w][g * 16 + l16][a1 * 4]);
      lsum[g] = __builtin_amdgcn_mfma_f32_16x16x32_bf16(pa0, ones, lsum[g], 0, 0, 0);
      lsum[g] = __builtin_amdgcn_mfma_f32_16x16x32_bf16(pa1, ones, lsum[g], 0, 0, 0);
#pragma unroll
      for (int dt = 0; dt < 4; ++dt) {
        const bf16x8 vb0 =
            *(const bf16x8*)(Vs[0] + (dt * 16 + l16) * 32 + quad * 8);
        const bf16x8 vb1 =
            *(const bf16x8*)(Vs[1] + (dt * 16 + l16) * 32 + quad * 8);
        o[g][dt] =
            __builtin_amdgcn_mfma_f32_16x16x32_bf16(pa0, vb0, o[g][dt], 0, 0, 0);
        o[g][dt] =
            __builtin_amdgcn_mfma_f32_16x16x32_bf16(pa1, vb1, o[g][dt], 0, 0, 0);
      }
    }
  }

  if (l16 == 0) {
#pragma unroll
    for (int g = 0; g < 2; ++g)
#pragma unroll
      for (int r = 0; r < 4; ++r)
        Lpart[((size_t)zs * 20 + h) * 1024 + qrow + g * 16 + quad * 4 + r] =
            lsum[g][r];
  }

  unsigned short* Op = Opart + (size_t)zs * 1024 * 1280;
#pragma unroll
  for (int g = 0; g < 2; ++g)
#pragma unroll
    for (int dt = 0; dt < 4; ++dt)
#pragma unroll
      for (int r = 0; r < 4; ++r)
        Op[(size_t)(qrow + g * 16 + quad * 4 + r) * 1280 + h * 64 + dt * 16 +
           l16] = f2bf(o[g][dt][r]);
}

// --------------------------- combine slice partials -------------------------
__global__ __launch_bounds__(BDIM) void k_combine(
    const unsigned short* __restrict__ Opart, const float* __restrict__ Lpart,
    unsigned short* __restrict__ attnb) {
  const int idx = blockIdx.x * BDIM + threadIdx.x;  // [0, 655360)
  const int row = idx / 160;
  const int c = (idx - row * 160) * 8;
  const int b = row >> 10, q = row & 1023, h = c >> 6;
  const int zb = (b >> 1) * 6 + (b & 1) * 2;  // 0,2,6,8
  const int ns = 2 + (b & 1) * 2;             // 2 or 4 slices
  float L = 0.f;
  float acc[8] = {0.f, 0.f, 0.f, 0.f, 0.f, 0.f, 0.f, 0.f};
  for (int s = 0; s < ns; ++s) {
    L += Lpart[((size_t)(zb + s) * 20 + h) * 1024 + q];
    const u16x8 v =
        *(const u16x8*)(Opart + (size_t)(zb + s) * 1310720 + (size_t)q * 1280 + c);
#pragma unroll
    for (int j = 0; j < 8; ++j) acc[j] += bf2f(v[j]);
  }
  const float rl = 1.0f / L;
  u16x8 o8;
#pragma unroll
  for (int j = 0; j < 8; ++j) o8[j] = f2bf(acc[j] * rl);
  *(u16x8*)(attnb + (size_t)row * 1280 + c) = o8;
}

// ---------------------------------------------------------------------------
extern "C" void kernel_launch(void* const* d_in, const int* in_sizes, int n_in,
                              void* d_out, int out_size, void* d_ws,
                              size_t ws_size, hipStream_t stream) {
  const float* X = (const float*)d_in[0];
  const float* Wq = (const float*)d_in[1];
  const float* Wk = (const float*)d_in[2];
  const float* Wv = (const float*)d_in[3];
  const float* Wo = (const float*)d_in[4];
  const float* bo = (const float*)d_in[5];
  float* out = (float*)d_out;

  char* ws = (char*)d_ws;
  size_t off = 0;
  auto alloc = [&](size_t bytes) {
    char* p = ws + off;
    off += (bytes + 255) & ~(size_t)255;
    return p;
  };
  unsigned short* Wcat = (unsigned short*)alloc(3840ull * 1280 * 2);
  unsigned short* Xbf = (unsigned short*)alloc(4096ull * 1280 * 2);
  unsigned short* QKV = (unsigned short*)alloc(4096ull * 3840 * 2);
  unsigned short* Wobf = (unsigned short*)alloc(1280ull * 1280 * 2);
  float* stats = (float*)alloc(2ull * 2 * 4 * 1280 * 4);
  unsigned short* qnb = (unsigned short*)alloc(4096ull * 1280 * 2);
  unsigned short* knb = (unsigned short*)alloc(4096ull * 1280 * 2);
  unsigned short* vtb = (unsigned short*)alloc(4096ull * 1280 * 2);
  unsigned short* attnb = (unsigned short*)alloc(4096ull * 1280 * 2);

  unsigned short* Opart = QKV;                        // 12 x 1024 x 1280 bf16
  float* Lpart = (float*)Wcat;                        // 12 x 20 x 1024 fp32
  float* psum = (float*)attnb;                        // 8 x 32 x 1280 fp32
  float* psq = (float*)(attnb + 4096ull * 1280 / 2);  // second half

  k_convert_all<<<11520, BDIM, 0, stream>>>(X, Wq, Wk, Wv, Wo, Xbf, Wcat, Wobf);
  k_gemm_bf16<<<dim3(32, 30), BDIM, 0, stream>>>(Xbf, Wcat, QKV, 4096, 3840,
                                                 1280);
  k_stats1<<<dim3(32, 8), 320, 0, stream>>>(QKV, psum, psq);
  k_stats2<<<dim3(5, 8), BDIM, 0, stream>>>(psum, psq, stats);
  k_adain_vt<<<11520, BDIM, 0, stream>>>(QKV, stats, qnb, knb, vtb);
  k_attn<<<dim3(8, 20, 12), BDIM, 0, stream>>>(qnb, knb, vtb, Opart, Lpart);
  k_combine<<<2560, BDIM, 0, stream>>>(Opart, Lpart, attnb);
  k_gemm_64x128<<<dim3(64, 10), BDIM, 0, stream>>>(attnb, Wobf, out, bo, 4096,
                                                   1280, 1280);
}